// Round 1
// baseline (2131.028 us; speedup 1.0000x reference)
//
#include <hip/hip_runtime.h>
#include <hip/hip_bf16.h>
#include <cstdint>

// MoE: 16384 tokens, d_model=1024, d_int=512, 8 experts, top-2.
// Baseline round: fp32 vector-ALU grouped GEMM (no fp32 MFMA on CDNA4).
// Pipeline: zero -> gate(top2) -> scan -> fill(buckets) -> fc1+swiglu -> fc2+combine(atomic).

#define NT 16384
#define DM 1024
#define DI 512
#define NE 8

// ---------------- small utility kernels ----------------

__global__ void zero_counts_kernel(int* __restrict__ counts) {
  if (threadIdx.x < NE) counts[threadIdx.x] = 0;
}

__global__ void zero_out_kernel(float4* __restrict__ out) {
  out[(size_t)blockIdx.x * blockDim.x + threadIdx.x] = make_float4(0.f, 0.f, 0.f, 0.f);
}

// ---------------- gate: scores -> softmax -> top2 -> renorm ----------------
// One wave per token. wg (8x1024, 32KB) staged in LDS.
__global__ __launch_bounds__(256) void gate_kernel(
    const float* __restrict__ x, const float* __restrict__ wg,
    int* __restrict__ topk_idx, float* __restrict__ topk_w,
    int* __restrict__ counts) {
  __shared__ float wgs[NE * DM];
  for (int i = threadIdx.x; i < NE * DM; i += 256) wgs[i] = wg[i];
  __syncthreads();
  const int wave = threadIdx.x >> 6;
  const int lane = threadIdx.x & 63;
  for (int t = blockIdx.x * 4 + wave; t < NT; t += gridDim.x * 4) {
    const float* __restrict__ xr = x + (size_t)t * DM;
    float acc[NE];
#pragma unroll
    for (int e = 0; e < NE; ++e) acc[e] = 0.f;
    for (int k = lane; k < DM; k += 64) {
      float xv = xr[k];
#pragma unroll
      for (int e = 0; e < NE; ++e) acc[e] += xv * wgs[e * DM + k];
    }
#pragma unroll
    for (int e = 0; e < NE; ++e) {
      float v = acc[e];
#pragma unroll
      for (int off = 32; off > 0; off >>= 1) v += __shfl_xor(v, off);
      acc[e] = v;
    }
    if (lane == 0) {
      // softmax probabilities (unnormalized suffices: renorm over top-2 cancels Z)
      float mx = acc[0];
#pragma unroll
      for (int e = 1; e < NE; ++e) mx = fmaxf(mx, acc[e]);
      float p[NE];
#pragma unroll
      for (int e = 0; e < NE; ++e) p[e] = __expf(acc[e] - mx);
      // top-2, ties -> lower index (matches jax.lax.top_k)
      int i0 = 0;
#pragma unroll
      for (int e = 1; e < NE; ++e) if (p[e] > p[i0]) i0 = e;
      int i1 = -1;
#pragma unroll
      for (int e = 0; e < NE; ++e) if (e != i0 && (i1 < 0 || p[e] > p[i1])) i1 = e;
      float s = p[i0] + p[i1];
      topk_idx[t * 2 + 0] = i0;
      topk_idx[t * 2 + 1] = i1;
      topk_w[t * 2 + 0] = p[i0] / s;
      topk_w[t * 2 + 1] = p[i1] / s;
      atomicAdd(&counts[i0], 1);
      atomicAdd(&counts[i1], 1);
    }
  }
}

// ---------------- scan: 8-entry exclusive prefix + cursor reset ----------------
__global__ void scan_kernel(const int* __restrict__ counts,
                            int* __restrict__ offsets, int* __restrict__ cursors) {
  if (threadIdx.x == 0) {
    int o = 0;
#pragma unroll
    for (int e = 0; e < NE; ++e) { offsets[e] = o; cursors[e] = 0; o += counts[e]; }
  }
}

// ---------------- fill: compact per-expert buckets (slot -> token, weight) ----------------
__global__ void fill_kernel(const int* __restrict__ topk_idx,
                            const float* __restrict__ topk_w,
                            const int* __restrict__ offsets,
                            int* __restrict__ cursors,
                            int* __restrict__ bucket_tok,
                            float* __restrict__ bucket_w) {
  int t = blockIdx.x * 256 + threadIdx.x;
  if (t >= NT) return;
#pragma unroll
  for (int j = 0; j < 2; ++j) {
    int e = topk_idx[t * 2 + j];
    float w = topk_w[t * 2 + j];
    int pos = atomicAdd(&cursors[e], 1);
    int slot = offsets[e] + pos;
    bucket_tok[slot] = t;
    bucket_w[slot] = w;
  }
}

// ---------------- pass 1: z = (x@fc1_y.T) * silu(x@fc1_g.T), grouped by expert ----------------
// grid = NE * 256(mtiles) * 8(ntiles); tile 64 tokens x 64 z-cols; K=1024 step 16.
// LDS pad 68 floats: rows 16B-aligned (272B) -> ds_read_b128; 2-way bank alias only (free).
__global__ __launch_bounds__(256) void expert_fc1_kernel(
    const float* __restrict__ x, const float* __restrict__ fc1,
    const int* __restrict__ counts, const int* __restrict__ offsets,
    const int* __restrict__ bucket_tok, float* __restrict__ z) {
  const int bid = blockIdx.x;
  const int e  = bid >> 11;
  const int r  = bid & 2047;
  const int mt = r >> 3;
  const int nt = r & 7;
  const int cnt = counts[e];
  const int m0 = mt * 64;
  if (m0 >= cnt) return;
  const int off = offsets[e];
  const int n0 = nt * 64;

  __shared__ float As[16][68];
  __shared__ float By[16][68];
  __shared__ float Bg[16][68];
  __shared__ int   toks[64];

  if (threadIdx.x < 64) {
    int m = m0 + threadIdx.x;
    toks[threadIdx.x] = (m < cnt) ? bucket_tok[off + m] : -1;
  }
  __syncthreads();

  const int tx = threadIdx.x & 15;   // -> 4 output cols
  const int ty = threadIdx.x >> 4;   // -> 4 output rows
  const int lm = threadIdx.x >> 2;   // staging row 0..63
  const int lk = (threadIdx.x & 3) << 2;  // staging k-quad

  const float* __restrict__ fc1e = fc1 + (size_t)e * (2 * DI) * DM;
  const int tokL = toks[lm];
  const float* __restrict__ aPtr  = (tokL >= 0) ? (x + (size_t)tokL * DM + lk) : nullptr;
  const float* __restrict__ byPtr = fc1e + (size_t)(n0 + lm) * DM + lk;
  const float* __restrict__ bgPtr = fc1e + (size_t)(DI + n0 + lm) * DM + lk;

  float accY[4][4] = {{0.f}};
  float accG[4][4] = {{0.f}};

  for (int k0 = 0; k0 < DM; k0 += 16) {
    float4 av = make_float4(0.f, 0.f, 0.f, 0.f);
    if (aPtr) av = *(const float4*)(aPtr + k0);
    const float4 yv = *(const float4*)(byPtr + k0);
    const float4 gv = *(const float4*)(bgPtr + k0);
    As[lk + 0][lm] = av.x; As[lk + 1][lm] = av.y; As[lk + 2][lm] = av.z; As[lk + 3][lm] = av.w;
    By[lk + 0][lm] = yv.x; By[lk + 1][lm] = yv.y; By[lk + 2][lm] = yv.z; By[lk + 3][lm] = yv.w;
    Bg[lk + 0][lm] = gv.x; Bg[lk + 1][lm] = gv.y; Bg[lk + 2][lm] = gv.z; Bg[lk + 3][lm] = gv.w;
    __syncthreads();
#pragma unroll
    for (int kk = 0; kk < 16; ++kk) {
      float4 a  = *(const float4*)&As[kk][ty * 4];
      float4 by = *(const float4*)&By[kk][tx * 4];
      float4 bg = *(const float4*)&Bg[kk][tx * 4];
      float aa[4] = {a.x, a.y, a.z, a.w};
      float bb[4] = {by.x, by.y, by.z, by.w};
      float gg[4] = {bg.x, bg.y, bg.z, bg.w};
#pragma unroll
      for (int i = 0; i < 4; ++i)
#pragma unroll
        for (int j = 0; j < 4; ++j) {
          accY[i][j] += aa[i] * bb[j];
          accG[i][j] += aa[i] * gg[j];
        }
    }
    __syncthreads();
  }

#pragma unroll
  for (int i = 0; i < 4; ++i) {
    int m = ty * 4 + i;
    if (m0 + m < cnt) {
      float o4[4];
#pragma unroll
      for (int j = 0; j < 4; ++j) {
        float g = accG[i][j];
        float sig = 1.f / (1.f + __expf(-g));
        o4[j] = accY[i][j] * g * sig;   // y * silu(g)
      }
      *(float4*)(z + (size_t)(off + m0 + m) * DI + n0 + tx * 4) =
          make_float4(o4[0], o4[1], o4[2], o4[3]);
    }
  }
}

// ---------------- pass 2: out[tok] += w * (z @ fc2[e].T), grouped by expert ----------------
// grid = NE * 256(mtiles) * 16(ntiles); tile 64 x 64; K=512 step 16.
__global__ __launch_bounds__(256) void expert_fc2_kernel(
    const float* __restrict__ z, const float* __restrict__ fc2,
    const int* __restrict__ counts, const int* __restrict__ offsets,
    const int* __restrict__ bucket_tok, const float* __restrict__ bucket_w,
    float* __restrict__ out) {
  const int bid = blockIdx.x;
  const int e  = bid >> 12;
  const int r  = bid & 4095;
  const int mt = r >> 4;
  const int nt = r & 15;
  const int cnt = counts[e];
  const int m0 = mt * 64;
  if (m0 >= cnt) return;
  const int off = offsets[e];
  const int n0 = nt * 64;

  __shared__ float As[16][68];
  __shared__ float Bs[16][68];
  __shared__ int   toks[64];
  __shared__ float wts[64];

  if (threadIdx.x < 64) {
    int m = m0 + threadIdx.x;
    bool ok = (m < cnt);
    toks[threadIdx.x] = ok ? bucket_tok[off + m] : -1;
    wts[threadIdx.x]  = ok ? bucket_w[off + m] : 0.f;
  }
  __syncthreads();

  const int tx = threadIdx.x & 15;
  const int ty = threadIdx.x >> 4;
  const int lm = threadIdx.x >> 2;
  const int lk = (threadIdx.x & 3) << 2;

  const bool rowOk = (m0 + lm) < cnt;
  const float* __restrict__ aPtr = z + (size_t)(off + m0 + lm) * DI + lk;
  const float* __restrict__ bPtr = fc2 + (size_t)e * DM * DI + (size_t)(n0 + lm) * DI + lk;

  float acc[4][4] = {{0.f}};

  for (int k0 = 0; k0 < DI; k0 += 16) {
    float4 av = make_float4(0.f, 0.f, 0.f, 0.f);
    if (rowOk) av = *(const float4*)(aPtr + k0);
    const float4 bv = *(const float4*)(bPtr + k0);
    As[lk + 0][lm] = av.x; As[lk + 1][lm] = av.y; As[lk + 2][lm] = av.z; As[lk + 3][lm] = av.w;
    Bs[lk + 0][lm] = bv.x; Bs[lk + 1][lm] = bv.y; Bs[lk + 2][lm] = bv.z; Bs[lk + 3][lm] = bv.w;
    __syncthreads();
#pragma unroll
    for (int kk = 0; kk < 16; ++kk) {
      float4 a = *(const float4*)&As[kk][ty * 4];
      float4 b = *(const float4*)&Bs[kk][tx * 4];
      float aa[4] = {a.x, a.y, a.z, a.w};
      float bb[4] = {b.x, b.y, b.z, b.w};
#pragma unroll
      for (int i = 0; i < 4; ++i)
#pragma unroll
        for (int j = 0; j < 4; ++j) acc[i][j] += aa[i] * bb[j];
    }
    __syncthreads();
  }

#pragma unroll
  for (int i = 0; i < 4; ++i) {
    int m = ty * 4 + i;
    if (m0 + m < cnt) {
      int tok = toks[m];
      float w = wts[m];
      float* __restrict__ orow = out + (size_t)tok * DM + n0 + tx * 4;
#pragma unroll
      for (int j = 0; j < 4; ++j) atomicAdd(&orow[j], w * acc[i][j]);
    }
  }
}

// ---------------- launch ----------------
extern "C" void kernel_launch(void* const* d_in, const int* in_sizes, int n_in,
                              void* d_out, int out_size, void* d_ws, size_t ws_size,
                              hipStream_t stream) {
  (void)in_sizes; (void)n_in; (void)out_size; (void)ws_size;
  const float* x   = (const float*)d_in[0];
  const float* wg  = (const float*)d_in[1];
  const float* fc1 = (const float*)d_in[2];
  const float* fc2 = (const float*)d_in[3];
  // d_in[4] = top_k scalar (=2, fixed by problem shape)
  float* out = (float*)d_out;

  // workspace layout (~67.7 MB)
  char* p = (char*)d_ws;
  float* z          = (float*)p; p += (size_t)2 * NT * DI * sizeof(float);  // 64 MB: 32768 x 512
  int*   topk_idx   = (int*)p;   p += (size_t)NT * 2 * sizeof(int);
  float* topk_w     = (float*)p; p += (size_t)NT * 2 * sizeof(float);
  int*   bucket_tok = (int*)p;   p += (size_t)2 * NT * sizeof(int);
  float* bucket_w   = (float*)p; p += (size_t)2 * NT * sizeof(float);
  int*   counts     = (int*)p;   p += NE * sizeof(int);
  int*   offsets    = (int*)p;   p += NE * sizeof(int);
  int*   cursors    = (int*)p;   p += NE * sizeof(int);

  zero_counts_kernel<<<1, 64, 0, stream>>>(counts);
  zero_out_kernel<<<(NT * DM / 4) / 256, 256, 0, stream>>>((float4*)out);
  gate_kernel<<<512, 256, 0, stream>>>(x, wg, topk_idx, topk_w, counts);
  scan_kernel<<<1, 64, 0, stream>>>(counts, offsets, cursors);
  fill_kernel<<<NT / 256, 256, 0, stream>>>(topk_idx, topk_w, offsets, cursors,
                                            bucket_tok, bucket_w);
  expert_fc1_kernel<<<NE * 256 * 8, 256, 0, stream>>>(x, fc1, counts, offsets,
                                                      bucket_tok, z);
  expert_fc2_kernel<<<NE * 256 * 16, 256, 0, stream>>>(z, fc2, counts, offsets,
                                                       bucket_tok, bucket_w, out);
}

// Round 2
// 866.652 us; speedup vs baseline: 2.4589x; 2.4589x over previous
//
#include <hip/hip_runtime.h>
#include <hip/hip_bf16.h>
#include <cstdint>

// MoE 16384x1024, d_int=512, 8 experts, top-2.
// Round 2: bf16 MFMA grouped GEMM (m97 structure: 128-tile, 16x16x32, global_load_lds w=16).
// Buckets keyed (slot j, expert e) -> 16 buckets; fc2 pass0 = plain store, pass1 = rmw add (no atomics).

#define NT 16384
#define DM 1024
#define DI 512
#define NE 8
#define NB 16     // (j,e) buckets
#define MT1 128   // max m-tiles per bucket (cnt <= 16384)

typedef __attribute__((ext_vector_type(8))) short bf16x8;
typedef __attribute__((ext_vector_type(4))) float f32x4;

__device__ __forceinline__ void gl16(const void* g, void* l) {
  __builtin_amdgcn_global_load_lds(
      (const __attribute__((address_space(1))) void*)g,
      (__attribute__((address_space(3))) void*)l, 16, 0, 0);
}

__device__ __forceinline__ ushort f2bf(float f) {
  uint32_t x = __float_as_uint(f);
  return (ushort)((x + 0x7fffu + ((x >> 16) & 1u)) >> 16);  // RNE, finite inputs
}

// ---------------- fp32 -> bf16 convert (8 elems/thread) ----------------
__global__ __launch_bounds__(256) void f2bf_kernel(const float* __restrict__ in,
                                                   ushort* __restrict__ out, int n8) {
  int i = blockIdx.x * 256 + threadIdx.x;
  if (i >= n8) return;
  const float4* p = (const float4*)(in + (size_t)i * 8);
  float4 a = p[0], b = p[1];
  union { ushort u[8]; int4 v; } o;
  o.u[0] = f2bf(a.x); o.u[1] = f2bf(a.y); o.u[2] = f2bf(a.z); o.u[3] = f2bf(a.w);
  o.u[4] = f2bf(b.x); o.u[5] = f2bf(b.y); o.u[6] = f2bf(b.z); o.u[7] = f2bf(b.w);
  *(int4*)(out + (size_t)i * 8) = o.v;
}

// ---------------- small utility kernels ----------------
__global__ void zero_counts_kernel(int* __restrict__ counts) {
  if (threadIdx.x < NB) counts[threadIdx.x] = 0;
}

// ---------------- gate (unchanged from round 1 except bucket keying) ----------------
__global__ __launch_bounds__(256) void gate_kernel(
    const float* __restrict__ x, const float* __restrict__ wg,
    int* __restrict__ topk_idx, float* __restrict__ topk_w,
    int* __restrict__ counts) {
  __shared__ float wgs[NE * DM];
  for (int i = threadIdx.x; i < NE * DM; i += 256) wgs[i] = wg[i];
  __syncthreads();
  const int wave = threadIdx.x >> 6;
  const int lane = threadIdx.x & 63;
  for (int t = blockIdx.x * 4 + wave; t < NT; t += gridDim.x * 4) {
    const float* __restrict__ xr = x + (size_t)t * DM;
    float acc[NE];
#pragma unroll
    for (int e = 0; e < NE; ++e) acc[e] = 0.f;
    for (int k = lane; k < DM; k += 64) {
      float xv = xr[k];
#pragma unroll
      for (int e = 0; e < NE; ++e) acc[e] += xv * wgs[e * DM + k];
    }
#pragma unroll
    for (int e = 0; e < NE; ++e) {
      float v = acc[e];
#pragma unroll
      for (int off = 32; off > 0; off >>= 1) v += __shfl_xor(v, off);
      acc[e] = v;
    }
    if (lane == 0) {
      float mx = acc[0];
#pragma unroll
      for (int e = 1; e < NE; ++e) mx = fmaxf(mx, acc[e]);
      float p[NE];
#pragma unroll
      for (int e = 0; e < NE; ++e) p[e] = __expf(acc[e] - mx);
      int i0 = 0;
#pragma unroll
      for (int e = 1; e < NE; ++e) if (p[e] > p[i0]) i0 = e;
      int i1 = -1;
#pragma unroll
      for (int e = 0; e < NE; ++e) if (e != i0 && (i1 < 0 || p[e] > p[i1])) i1 = e;
      float s = p[i0] + p[i1];
      topk_idx[t * 2 + 0] = i0;
      topk_idx[t * 2 + 1] = i1;
      topk_w[t * 2 + 0] = p[i0] / s;
      topk_w[t * 2 + 1] = p[i1] / s;
      atomicAdd(&counts[i0], 1);        // bucket (j=0, e=i0)
      atomicAdd(&counts[8 + i1], 1);    // bucket (j=1, e=i1)
    }
  }
}

__global__ void scan_kernel(const int* __restrict__ counts,
                            int* __restrict__ offsets, int* __restrict__ cursors) {
  if (threadIdx.x == 0) {
    int o = 0;
#pragma unroll
    for (int b = 0; b < NB; ++b) { offsets[b] = o; cursors[b] = 0; o += counts[b]; }
  }
}

__global__ void fill_kernel(const int* __restrict__ topk_idx,
                            const float* __restrict__ topk_w,
                            const int* __restrict__ offsets,
                            int* __restrict__ cursors,
                            int* __restrict__ bucket_tok,
                            float* __restrict__ bucket_w) {
  int t = blockIdx.x * 256 + threadIdx.x;
  if (t >= NT) return;
#pragma unroll
  for (int j = 0; j < 2; ++j) {
    int e = topk_idx[t * 2 + j];
    int b = j * 8 + e;
    int pos = atomicAdd(&cursors[b], 1);
    int slot = offsets[b] + pos;
    bucket_tok[slot] = t;
    bucket_w[slot] = topk_w[t * 2 + j];
  }
}

// ---------------- fc1 + swiglu: z[slot] = y * silu(g), tile 128 tok x 64 zcols ----------------
// A: gathered x rows (bf16), By/Bg: fc1 weight rows. K=1024, BK=32.
__global__ __launch_bounds__(256) void fc1_kernel(
    const ushort* __restrict__ xb, const ushort* __restrict__ fc1b,
    const int* __restrict__ counts, const int* __restrict__ offsets,
    const int* __restrict__ bucket_tok, ushort* __restrict__ z) {
  const int bid = blockIdx.x;
  const int b   = bid >> 10;            // / (128 mt * 8 nt)
  const int rem = bid & 1023;
  const int mt  = rem >> 3;
  const int nt  = rem & 7;
  const int cnt = counts[b];
  const int m0  = mt << 7;
  if (m0 >= cnt) return;
  const int off = offsets[b];
  const int e   = b & 7;
  const int n0  = nt << 6;              // z-col base (0..448)

  __shared__ ushort As[128 * 32];
  __shared__ ushort By[64 * 32];
  __shared__ ushort Bg[64 * 32];
  __shared__ int toks[128];

  const int t = threadIdx.x;
  if (t < 128) {
    int m = m0 + t;
    toks[t] = bucket_tok[off + ((m < cnt) ? m : (cnt - 1))];
  }
  __syncthreads();

  // staging roles: 16B per thread; row = t/4, k-chunk = (t&3)*8 bf16
  const int srow = t >> 2;
  const int skq  = (t & 3) * 8;
  const ushort* aG0 = xb + (size_t)toks[srow] * DM + skq;
  const ushort* aG1 = xb + (size_t)toks[64 + srow] * DM + skq;
  const ushort* fe  = fc1b + (size_t)e * (2 * DI) * DM;
  const ushort* byG = fe + (size_t)(n0 + srow) * DM + skq;
  const ushort* bgG = fe + (size_t)(DI + n0 + srow) * DM + skq;

  const int wave = t >> 6, lane = t & 63;
  const int moff = (wave >> 1) * 64;    // wave 2x2 over 128x64
  const int noff = (wave & 1) * 32;
  const int fr = lane & 15;
  const int fg = lane >> 4;

  f32x4 accY[4][2], accG[4][2];
#pragma unroll
  for (int i = 0; i < 4; ++i)
#pragma unroll
    for (int j = 0; j < 2; ++j) { accY[i][j] = (f32x4)0.f; accG[i][j] = (f32x4)0.f; }

  const ushort* aRd  = As + (moff + fr) * 32 + fg * 8;
  const ushort* byRd = By + (noff + fr) * 32 + fg * 8;
  const ushort* bgRd = Bg + (noff + fr) * 32 + fg * 8;
  char* AsW = (char*)As + wave * 1024;
  char* ByW = (char*)By + wave * 1024;
  char* BgW = (char*)Bg + wave * 1024;

  for (int k0 = 0; k0 < DM; k0 += 32) {
    gl16(aG0 + k0, AsW);
    gl16(aG1 + k0, AsW + 4096);
    gl16(byG + k0, ByW);
    gl16(bgG + k0, BgW);
    __syncthreads();   // compiler drains vmcnt before s_barrier
    bf16x8 a[4], by[2], bg[2];
#pragma unroll
    for (int i = 0; i < 4; ++i) a[i] = *(const bf16x8*)(aRd + i * 16 * 32);
#pragma unroll
    for (int j = 0; j < 2; ++j) {
      by[j] = *(const bf16x8*)(byRd + j * 16 * 32);
      bg[j] = *(const bf16x8*)(bgRd + j * 16 * 32);
    }
#pragma unroll
    for (int i = 0; i < 4; ++i)
#pragma unroll
      for (int j = 0; j < 2; ++j) {
        accY[i][j] = __builtin_amdgcn_mfma_f32_16x16x32_bf16(a[i], by[j], accY[i][j], 0, 0, 0);
        accG[i][j] = __builtin_amdgcn_mfma_f32_16x16x32_bf16(a[i], bg[j], accG[i][j], 0, 0, 0);
      }
    __syncthreads();
  }

  // epilogue: z = y * silu(g) as bf16. C/D map: col=lane&15, row=fg*4+reg (m89).
#pragma unroll
  for (int i = 0; i < 4; ++i)
#pragma unroll
    for (int r = 0; r < 4; ++r) {
      int m = moff + i * 16 + fg * 4 + r;
      if (m0 + m < cnt) {
        ushort* zrow = z + (size_t)(off + m0 + m) * DI + n0 + noff + fr;
#pragma unroll
        for (int j = 0; j < 2; ++j) {
          float y = accY[i][j][r], g = accG[i][j][r];
          float zz = y * g / (1.f + __expf(-g));
          zrow[j * 16] = f2bf(zz);
        }
      }
    }
}

// ---------------- fc2: out[tok] (=|+=) w * (z @ fc2[e].T), tile 128x128, K=512 ----------------
template <bool ADD>
__global__ __launch_bounds__(256) void fc2_kernel(
    const ushort* __restrict__ z, const ushort* __restrict__ fc2b,
    const int* __restrict__ counts, const int* __restrict__ offsets,
    const int* __restrict__ bucket_tok, const float* __restrict__ bucket_w,
    float* __restrict__ out, int bucket_base) {
  const int bid = blockIdx.x;
  const int b   = bucket_base + (bid >> 10);
  const int rem = bid & 1023;
  const int mt  = rem >> 3;
  const int nt  = rem & 7;
  const int cnt = counts[b];
  const int m0  = mt << 7;
  if (m0 >= cnt) return;
  const int off = offsets[b];
  const int e   = b & 7;
  const int n0  = nt << 7;              // out-col base

  __shared__ ushort As[128 * 32];
  __shared__ ushort Bs[128 * 32];
  __shared__ int toks[128];
  __shared__ float wts[128];

  const int t = threadIdx.x;
  if (t < 128) {
    int m = m0 + t;
    int mm = (m < cnt) ? m : (cnt - 1);
    toks[t] = bucket_tok[off + mm];
    wts[t]  = bucket_w[off + mm];
  }
  __syncthreads();

  const int srow = t >> 2;
  const int skq  = (t & 3) * 8;
  const ushort* aG = z + (size_t)(off + m0 + srow) * DI + skq;       // contiguous slots
  const ushort* bG = fc2b + (size_t)e * DM * DI + (size_t)(n0 + srow) * DI + skq;

  const int wave = t >> 6, lane = t & 63;
  const int moff = (wave >> 1) * 64;
  const int noff = (wave & 1) * 64;
  const int fr = lane & 15;
  const int fg = lane >> 4;

  f32x4 acc[4][4];
#pragma unroll
  for (int i = 0; i < 4; ++i)
#pragma unroll
    for (int j = 0; j < 4; ++j) acc[i][j] = (f32x4)0.f;

  const ushort* aRd = As + (moff + fr) * 32 + fg * 8;
  const ushort* bRd = Bs + (noff + fr) * 32 + fg * 8;
  char* AsW = (char*)As + wave * 1024;
  char* BsW = (char*)Bs + wave * 1024;

  for (int k0 = 0; k0 < DI; k0 += 32) {
    gl16(aG + k0, AsW);
    gl16(aG + (size_t)64 * DI + k0, AsW + 4096);
    gl16(bG + k0, BsW);
    gl16(bG + (size_t)64 * DI + k0, BsW + 4096);
    __syncthreads();
    bf16x8 a[4], bb[4];
#pragma unroll
    for (int i = 0; i < 4; ++i) a[i] = *(const bf16x8*)(aRd + i * 16 * 32);
#pragma unroll
    for (int j = 0; j < 4; ++j) bb[j] = *(const bf16x8*)(bRd + j * 16 * 32);
#pragma unroll
    for (int i = 0; i < 4; ++i)
#pragma unroll
      for (int j = 0; j < 4; ++j)
        acc[i][j] = __builtin_amdgcn_mfma_f32_16x16x32_bf16(a[i], bb[j], acc[i][j], 0, 0, 0);
    __syncthreads();
  }

#pragma unroll
  for (int i = 0; i < 4; ++i)
#pragma unroll
    for (int r = 0; r < 4; ++r) {
      int m = moff + i * 16 + fg * 4 + r;
      if (m0 + m < cnt) {
        int tok = toks[m];
        float w = wts[m];
        float* orow = out + (size_t)tok * DM + n0 + noff + fr;
#pragma unroll
        for (int j = 0; j < 4; ++j) {
          float v = w * acc[i][j][r];
          if (ADD) orow[j * 16] += v;
          else     orow[j * 16] = v;
        }
      }
    }
}

// ---------------- launch ----------------
extern "C" void kernel_launch(void* const* d_in, const int* in_sizes, int n_in,
                              void* d_out, int out_size, void* d_ws, size_t ws_size,
                              hipStream_t stream) {
  (void)in_sizes; (void)n_in; (void)out_size; (void)ws_size;
  const float* x   = (const float*)d_in[0];
  const float* wg  = (const float*)d_in[1];
  const float* fc1 = (const float*)d_in[2];
  const float* fc2 = (const float*)d_in[3];
  float* out = (float*)d_out;

  // workspace (~93 MB)
  char* p = (char*)d_ws;
  ushort* xb   = (ushort*)p; p += (size_t)NT * DM * 2;                    // 33.6 MB
  ushort* fc1b = (ushort*)p; p += (size_t)NE * 2 * DI * DM * 2;          // 16.8 MB
  ushort* fc2b = (ushort*)p; p += (size_t)NE * DM * DI * 2;              // 8.4 MB
  ushort* z    = (ushort*)p; p += ((size_t)2 * NT + 128) * DI * 2;       // 33.7 MB (+slack)
  int*   topk_idx   = (int*)p;   p += (size_t)NT * 2 * 4;
  float* topk_w     = (float*)p; p += (size_t)NT * 2 * 4;
  int*   bucket_tok = (int*)p;   p += (size_t)2 * NT * 4;
  float* bucket_w   = (float*)p; p += (size_t)2 * NT * 4;
  int*   counts     = (int*)p;   p += NB * 4;
  int*   offsets    = (int*)p;   p += NB * 4;
  int*   cursors    = (int*)p;   p += NB * 4;

  f2bf_kernel<<<(NT * DM / 8 + 255) / 256, 256, 0, stream>>>(x, xb, NT * DM / 8);
  f2bf_kernel<<<(NE * 2 * DI * DM / 8 + 255) / 256, 256, 0, stream>>>(fc1, fc1b, NE * 2 * DI * DM / 8);
  f2bf_kernel<<<(NE * DM * DI / 8 + 255) / 256, 256, 0, stream>>>(fc2, fc2b, NE * DM * DI / 8);

  zero_counts_kernel<<<1, 64, 0, stream>>>(counts);
  gate_kernel<<<512, 256, 0, stream>>>(x, wg, topk_idx, topk_w, counts);
  scan_kernel<<<1, 64, 0, stream>>>(counts, offsets, cursors);
  fill_kernel<<<NT / 256, 256, 0, stream>>>(topk_idx, topk_w, offsets, cursors,
                                            bucket_tok, bucket_w);

  fc1_kernel<<<NB * MT1 * 8, 256, 0, stream>>>(xb, fc1b, counts, offsets, bucket_tok, z);
  fc2_kernel<false><<<8 * MT1 * 8, 256, 0, stream>>>(z, fc2b, counts, offsets,
                                                     bucket_tok, bucket_w, out, 0);
  fc2_kernel<true><<<8 * MT1 * 8, 256, 0, stream>>>(z, fc2b, counts, offsets,
                                                    bucket_tok, bucket_w, out, 8);
}

// Round 5
// 417.688 us; speedup vs baseline: 5.1020x; 2.0749x over previous
//
#include <hip/hip_runtime.h>
#include <hip/hip_bf16.h>
#include <cstdint>

// MoE 16384x1024, d_int=512, 8 experts, top-2.
// Round 3 (2nd resubmit; r3/r4 benches timed out on GPU acquisition): atomic-free routing.
// gate: no atomics + fused x->bf16 conversion. Routing via per-block histogram + scan + LDS cursors.

#define NT 16384
#define DM 1024
#define DI 512
#define NE 8
#define NB 16     // (j,e) buckets
#define HB 64     // histogram blocks (256 tokens each)
#define MT1 128   // max m-tiles per bucket

typedef __attribute__((ext_vector_type(8))) short bf16x8;
typedef __attribute__((ext_vector_type(4))) float f32x4;

__device__ __forceinline__ void gl16(const void* g, void* l) {
  __builtin_amdgcn_global_load_lds(
      (const __attribute__((address_space(1))) void*)g,
      (__attribute__((address_space(3))) void*)l, 16, 0, 0);
}

__device__ __forceinline__ ushort f2bf(float f) {
  uint32_t x = __float_as_uint(f);
  return (ushort)((x + 0x7fffu + ((x >> 16) & 1u)) >> 16);  // RNE, finite inputs
}

// ---------------- fp32 -> bf16 convert (weights only; x fused into gate) ----------------
__global__ __launch_bounds__(256) void f2bf_kernel(const float* __restrict__ in,
                                                   ushort* __restrict__ out, int n8) {
  int i = blockIdx.x * 256 + threadIdx.x;
  if (i >= n8) return;
  const float4* p = (const float4*)(in + (size_t)i * 8);
  float4 a = p[0], b = p[1];
  union { ushort u[8]; int4 v; } o;
  o.u[0] = f2bf(a.x); o.u[1] = f2bf(a.y); o.u[2] = f2bf(a.z); o.u[3] = f2bf(a.w);
  o.u[4] = f2bf(b.x); o.u[5] = f2bf(b.y); o.u[6] = f2bf(b.z); o.u[7] = f2bf(b.w);
  *(int4*)(out + (size_t)i * 8) = o.v;
}

// ---------------- gate: scores -> top2 -> renorm; fused x->bf16. NO atomics. ----------------
__global__ __launch_bounds__(256) void gate_kernel(
    const float* __restrict__ x, const float* __restrict__ wg,
    int* __restrict__ topk_idx, float* __restrict__ topk_w,
    ushort* __restrict__ xb) {
  __shared__ float wgs[NE * DM];
  for (int i = threadIdx.x; i < NE * DM; i += 256) wgs[i] = wg[i];
  __syncthreads();
  const int wave = threadIdx.x >> 6;
  const int lane = threadIdx.x & 63;
  const int wid = blockIdx.x * 4 + wave;   // 4096 waves, 4 tokens each
  for (int g = 0; g < 4; ++g) {
    const int t = wid * 4 + g;
    const float* __restrict__ xr = x + (size_t)t * DM;
    ushort* __restrict__ xw = xb + (size_t)t * DM;
    float acc[NE];
#pragma unroll
    for (int e = 0; e < NE; ++e) acc[e] = 0.f;
#pragma unroll
    for (int it = 0; it < DM / 64; ++it) {
      int k = lane + it * 64;
      float xv = xr[k];
      xw[k] = f2bf(xv);
#pragma unroll
      for (int e = 0; e < NE; ++e) acc[e] += xv * wgs[e * DM + k];
    }
#pragma unroll
    for (int e = 0; e < NE; ++e) {
      float v = acc[e];
#pragma unroll
      for (int off = 32; off > 0; off >>= 1) v += __shfl_xor(v, off);
      acc[e] = v;
    }
    if (lane == 0) {
      float mx = acc[0];
#pragma unroll
      for (int e = 1; e < NE; ++e) mx = fmaxf(mx, acc[e]);
      float p[NE];
#pragma unroll
      for (int e = 0; e < NE; ++e) p[e] = __expf(acc[e] - mx);
      int i0 = 0;
#pragma unroll
      for (int e = 1; e < NE; ++e) if (p[e] > p[i0]) i0 = e;
      int i1 = -1;
#pragma unroll
      for (int e = 0; e < NE; ++e) if (e != i0 && (i1 < 0 || p[e] > p[i1])) i1 = e;
      float s = p[i0] + p[i1];
      topk_idx[t * 2 + 0] = i0;
      topk_idx[t * 2 + 1] = i1;
      topk_w[t * 2 + 0] = p[i0] / s;
      topk_w[t * 2 + 1] = p[i1] / s;
    }
  }
}

// ---------------- hist: per-block bucket counts (LDS atomics only) ----------------
__global__ __launch_bounds__(256) void hist_kernel(const int* __restrict__ topk_idx,
                                                   int* __restrict__ blkcnt) {
  __shared__ int lc[NB];
  if (threadIdx.x < NB) lc[threadIdx.x] = 0;
  __syncthreads();
  int t = blockIdx.x * 256 + threadIdx.x;
  int e0 = topk_idx[t * 2 + 0];
  int e1 = topk_idx[t * 2 + 1];
  atomicAdd(&lc[e0], 1);
  atomicAdd(&lc[8 + e1], 1);
  __syncthreads();
  if (threadIdx.x < NB) blkcnt[blockIdx.x * NB + threadIdx.x] = lc[threadIdx.x];
}

// ---------------- scan2: totals, bucket offsets, per-block bases ----------------
__global__ void scan2_kernel(const int* __restrict__ blkcnt, int* __restrict__ counts,
                             int* __restrict__ offsets, int* __restrict__ blk_base) {
  __shared__ int tot[NB];
  __shared__ int offs[NB];
  const int i = threadIdx.x;
  if (i < NB) {
    int s = 0;
    for (int b = 0; b < HB; ++b) s += blkcnt[b * NB + i];
    tot[i] = s;
    counts[i] = s;
  }
  __syncthreads();
  if (i == 0) {
    int o = 0;
    for (int b = 0; b < NB; ++b) { offs[b] = o; offsets[b] = o; o += tot[b]; }
  }
  __syncthreads();
  if (i < NB) {
    int o = offs[i];
    for (int b = 0; b < HB; ++b) { blk_base[b * NB + i] = o; o += blkcnt[b * NB + i]; }
  }
}

// ---------------- fill: LDS cursors + precomputed bases. NO global atomics. ----------------
__global__ __launch_bounds__(256) void fill_kernel(
    const int* __restrict__ topk_idx, const float* __restrict__ topk_w,
    const int* __restrict__ blk_base, int* __restrict__ bucket_tok,
    float* __restrict__ bucket_w) {
  __shared__ int lcur[NB];
  if (threadIdx.x < NB) lcur[threadIdx.x] = 0;
  __syncthreads();
  int t = blockIdx.x * 256 + threadIdx.x;
#pragma unroll
  for (int j = 0; j < 2; ++j) {
    int e = topk_idx[t * 2 + j];
    int b = j * 8 + e;
    int pos = atomicAdd(&lcur[b], 1);               // LDS atomic: cheap, local
    int slot = blk_base[blockIdx.x * NB + b] + pos;
    bucket_tok[slot] = t;
    bucket_w[slot] = topk_w[t * 2 + j];
  }
}

// ---------------- fc1 + swiglu: z[slot] = y * silu(g), tile 128 tok x 64 zcols ----------------
__global__ __launch_bounds__(256) void fc1_kernel(
    const ushort* __restrict__ xb, const ushort* __restrict__ fc1b,
    const int* __restrict__ counts, const int* __restrict__ offsets,
    const int* __restrict__ bucket_tok, ushort* __restrict__ z) {
  const int bid = blockIdx.x;
  const int b   = bid >> 10;
  const int rem = bid & 1023;
  const int mt  = rem >> 3;
  const int nt  = rem & 7;
  const int cnt = counts[b];
  const int m0  = mt << 7;
  if (m0 >= cnt) return;
  const int off = offsets[b];
  const int e   = b & 7;
  const int n0  = nt << 6;

  __shared__ ushort As[128 * 32];
  __shared__ ushort By[64 * 32];
  __shared__ ushort Bg[64 * 32];
  __shared__ int toks[128];

  const int t = threadIdx.x;
  if (t < 128) {
    int m = m0 + t;
    toks[t] = bucket_tok[off + ((m < cnt) ? m : (cnt - 1))];
  }
  __syncthreads();

  const int srow = t >> 2;
  const int skq  = (t & 3) * 8;
  const ushort* aG0 = xb + (size_t)toks[srow] * DM + skq;
  const ushort* aG1 = xb + (size_t)toks[64 + srow] * DM + skq;
  const ushort* fe  = fc1b + (size_t)e * (2 * DI) * DM;
  const ushort* byG = fe + (size_t)(n0 + srow) * DM + skq;
  const ushort* bgG = fe + (size_t)(DI + n0 + srow) * DM + skq;

  const int wave = t >> 6, lane = t & 63;
  const int moff = (wave >> 1) * 64;
  const int noff = (wave & 1) * 32;
  const int fr = lane & 15;
  const int fg = lane >> 4;

  f32x4 accY[4][2], accG[4][2];
#pragma unroll
  for (int i = 0; i < 4; ++i)
#pragma unroll
    for (int j = 0; j < 2; ++j) { accY[i][j] = (f32x4)0.f; accG[i][j] = (f32x4)0.f; }

  const ushort* aRd  = As + (moff + fr) * 32 + fg * 8;
  const ushort* byRd = By + (noff + fr) * 32 + fg * 8;
  const ushort* bgRd = Bg + (noff + fr) * 32 + fg * 8;
  char* AsW = (char*)As + wave * 1024;
  char* ByW = (char*)By + wave * 1024;
  char* BgW = (char*)Bg + wave * 1024;

  for (int k0 = 0; k0 < DM; k0 += 32) {
    gl16(aG0 + k0, AsW);
    gl16(aG1 + k0, AsW + 4096);
    gl16(byG + k0, ByW);
    gl16(bgG + k0, BgW);
    __syncthreads();
    bf16x8 a[4], by[2], bg[2];
#pragma unroll
    for (int i = 0; i < 4; ++i) a[i] = *(const bf16x8*)(aRd + i * 16 * 32);
#pragma unroll
    for (int j = 0; j < 2; ++j) {
      by[j] = *(const bf16x8*)(byRd + j * 16 * 32);
      bg[j] = *(const bf16x8*)(bgRd + j * 16 * 32);
    }
#pragma unroll
    for (int i = 0; i < 4; ++i)
#pragma unroll
      for (int j = 0; j < 2; ++j) {
        accY[i][j] = __builtin_amdgcn_mfma_f32_16x16x32_bf16(a[i], by[j], accY[i][j], 0, 0, 0);
        accG[i][j] = __builtin_amdgcn_mfma_f32_16x16x32_bf16(a[i], bg[j], accG[i][j], 0, 0, 0);
      }
    __syncthreads();
  }

#pragma unroll
  for (int i = 0; i < 4; ++i)
#pragma unroll
    for (int r = 0; r < 4; ++r) {
      int m = moff + i * 16 + fg * 4 + r;
      if (m0 + m < cnt) {
        ushort* zrow = z + (size_t)(off + m0 + m) * DI + n0 + noff + fr;
#pragma unroll
        for (int j = 0; j < 2; ++j) {
          float y = accY[i][j][r], g = accG[i][j][r];
          float zz = y * g / (1.f + __expf(-g));
          zrow[j * 16] = f2bf(zz);
        }
      }
    }
}

// ---------------- fc2: out[tok] (=|+=) w * (z @ fc2[e].T), tile 128x128, K=512 ----------------
template <bool ADD>
__global__ __launch_bounds__(256) void fc2_kernel(
    const ushort* __restrict__ z, const ushort* __restrict__ fc2b,
    const int* __restrict__ counts, const int* __restrict__ offsets,
    const int* __restrict__ bucket_tok, const float* __restrict__ bucket_w,
    float* __restrict__ out, int bucket_base) {
  const int bid = blockIdx.x;
  const int b   = bucket_base + (bid >> 10);
  const int rem = bid & 1023;
  const int mt  = rem >> 3;
  const int nt  = rem & 7;
  const int cnt = counts[b];
  const int m0  = mt << 7;
  if (m0 >= cnt) return;
  const int off = offsets[b];
  const int e   = b & 7;
  const int n0  = nt << 7;

  __shared__ ushort As[128 * 32];
  __shared__ ushort Bs[128 * 32];
  __shared__ int toks[128];
  __shared__ float wts[128];

  const int t = threadIdx.x;
  if (t < 128) {
    int m = m0 + t;
    int mm = (m < cnt) ? m : (cnt - 1);
    toks[t] = bucket_tok[off + mm];
    wts[t]  = bucket_w[off + mm];
  }
  __syncthreads();

  const int srow = t >> 2;
  const int skq  = (t & 3) * 8;
  const ushort* aG = z + (size_t)(off + m0 + srow) * DI + skq;
  const ushort* bG = fc2b + (size_t)e * DM * DI + (size_t)(n0 + srow) * DI + skq;

  const int wave = t >> 6, lane = t & 63;
  const int moff = (wave >> 1) * 64;
  const int noff = (wave & 1) * 64;
  const int fr = lane & 15;
  const int fg = lane >> 4;

  f32x4 acc[4][4];
#pragma unroll
  for (int i = 0; i < 4; ++i)
#pragma unroll
    for (int j = 0; j < 4; ++j) acc[i][j] = (f32x4)0.f;

  const ushort* aRd = As + (moff + fr) * 32 + fg * 8;
  const ushort* bRd = Bs + (noff + fr) * 32 + fg * 8;
  char* AsW = (char*)As + wave * 1024;
  char* BsW = (char*)Bs + wave * 1024;

  for (int k0 = 0; k0 < DI; k0 += 32) {
    gl16(aG + k0, AsW);
    gl16(aG + (size_t)64 * DI + k0, AsW + 4096);
    gl16(bG + k0, BsW);
    gl16(bG + (size_t)64 * DI + k0, BsW + 4096);
    __syncthreads();
    bf16x8 a[4], bb[4];
#pragma unroll
    for (int i = 0; i < 4; ++i) a[i] = *(const bf16x8*)(aRd + i * 16 * 32);
#pragma unroll
    for (int j = 0; j < 4; ++j) bb[j] = *(const bf16x8*)(bRd + j * 16 * 32);
#pragma unroll
    for (int i = 0; i < 4; ++i)
#pragma unroll
      for (int j = 0; j < 4; ++j)
        acc[i][j] = __builtin_amdgcn_mfma_f32_16x16x32_bf16(a[i], bb[j], acc[i][j], 0, 0, 0);
    __syncthreads();
  }

#pragma unroll
  for (int i = 0; i < 4; ++i)
#pragma unroll
    for (int r = 0; r < 4; ++r) {
      int m = moff + i * 16 + fg * 4 + r;
      if (m0 + m < cnt) {
        int tok = toks[m];
        float w = wts[m];
        float* orow = out + (size_t)tok * DM + n0 + noff + fr;
#pragma unroll
        for (int j = 0; j < 4; ++j) {
          float v = w * acc[i][j][r];
          if (ADD) orow[j * 16] += v;
          else     orow[j * 16] = v;
        }
      }
    }
}

// ---------------- launch ----------------
extern "C" void kernel_launch(void* const* d_in, const int* in_sizes, int n_in,
                              void* d_out, int out_size, void* d_ws, size_t ws_size,
                              hipStream_t stream) {
  (void)in_sizes; (void)n_in; (void)out_size; (void)ws_size;
  const float* x   = (const float*)d_in[0];
  const float* wg  = (const float*)d_in[1];
  const float* fc1 = (const float*)d_in[2];
  const float* fc2 = (const float*)d_in[3];
  float* out = (float*)d_out;

  char* p = (char*)d_ws;
  ushort* xb   = (ushort*)p; p += (size_t)NT * DM * 2;
  ushort* fc1b = (ushort*)p; p += (size_t)NE * 2 * DI * DM * 2;
  ushort* fc2b = (ushort*)p; p += (size_t)NE * DM * DI * 2;
  ushort* z    = (ushort*)p; p += ((size_t)2 * NT + 128) * DI * 2;
  int*   topk_idx   = (int*)p;   p += (size_t)NT * 2 * 4;
  float* topk_w     = (float*)p; p += (size_t)NT * 2 * 4;
  int*   bucket_tok = (int*)p;   p += (size_t)2 * NT * 4;
  float* bucket_w   = (float*)p; p += (size_t)2 * NT * 4;
  int*   counts     = (int*)p;   p += NB * 4;
  int*   offsets    = (int*)p;   p += NB * 4;
  int*   blkcnt     = (int*)p;   p += HB * NB * 4;
  int*   blk_base   = (int*)p;   p += HB * NB * 4;

  f2bf_kernel<<<(NE * 2 * DI * DM / 8 + 255) / 256, 256, 0, stream>>>(fc1, fc1b, NE * 2 * DI * DM / 8);
  f2bf_kernel<<<(NE * DM * DI / 8 + 255) / 256, 256, 0, stream>>>(fc2, fc2b, NE * DM * DI / 8);

  gate_kernel<<<1024, 256, 0, stream>>>(x, wg, topk_idx, topk_w, xb);
  hist_kernel<<<HB, 256, 0, stream>>>(topk_idx, blkcnt);
  scan2_kernel<<<1, 64, 0, stream>>>(blkcnt, counts, offsets, blk_base);
  fill_kernel<<<HB, 256, 0, stream>>>(topk_idx, topk_w, blk_base, bucket_tok, bucket_w);

  fc1_kernel<<<NB * MT1 * 8, 256, 0, stream>>>(xb, fc1b, counts, offsets, bucket_tok, z);
  fc2_kernel<false><<<8 * MT1 * 8, 256, 0, stream>>>(z, fc2b, counts, offsets,
                                                     bucket_tok, bucket_w, out, 0);
  fc2_kernel<true><<<8 * MT1 * 8, 256, 0, stream>>>(z, fc2b, counts, offsets,
                                                    bucket_tok, bucket_w, out, 8);
}